// Round 7
// baseline (261.183 us; speedup 1.0000x reference)
//
#include <hip/hip_runtime.h>
#include <stdint.h>

#define N_NODES 50000
#define N_PAD   50048     // 391 * 128
#define F_IN 512
#define H_DIM 256
#define C_DIM 16

typedef __attribute__((ext_vector_type(8))) short short8;
typedef __attribute__((ext_vector_type(4))) float f32x4;
typedef __attribute__((ext_vector_type(4))) unsigned short us4;
typedef __attribute__((ext_vector_type(8))) unsigned short us8;

__device__ inline float bf2f(unsigned short u) {
    return __uint_as_float(((uint32_t)u) << 16);
}
__device__ inline unsigned short f2bf(float f) {
    uint32_t u = __float_as_uint(f);
    u += 0x7FFFu + ((u >> 16) & 1u);   // round-to-nearest-even
    return (unsigned short)(u >> 16);
}
__device__ inline int eidx(const void* p, long long i, int is64) {
    return is64 ? (int)((const long long*)p)[i] : ((const int*)p)[i];
}

// async global->LDS, 16B per lane, linear LDS dest (wave base + lane*16)
#define GLOAD16(gp, lp)                                                       \
    __builtin_amdgcn_global_load_lds(                                         \
        (const __attribute__((address_space(1))) void*)(gp),                  \
        (__attribute__((address_space(3))) void*)(lp), 16, 0, 0)

// ---------- fused prep: dtype detect + W transpose-convert + cnt/cur zero --

__global__ void prep_k(const void* ei, int* flag,
                       const float* w1, unsigned short* w1t,
                       const float* w2, unsigned short* w2t,
                       int* cnt, int* cur) {
    int i = blockIdx.x * 256 + threadIdx.x;
    if (i == 0) {
        const uint32_t* w = (const uint32_t*)ei;
        int is64 = 1;
        for (int j = 1; j < 128; j += 2)
            if (w[j] != 0u) { is64 = 0; break; }
        *flag = is64;
    }
    if (i < N_NODES) { cnt[i] = 0; cur[i] = 0; }
    if (i < F_IN * H_DIM) {
        int k = i / H_DIM, n = i % H_DIM;
        w1t[n * F_IN + k] = f2bf(w1[i]);
    }
    if (i < H_DIM * C_DIM) {
        int k = i / C_DIM, n = i % C_DIM;
        w2t[n * H_DIM + k] = f2bf(w2[i]);
    }
}

// ---------- x fp32 -> bf16 streaming convert (also zeroes the pad rows) ----

__global__ __launch_bounds__(256) void xconv_k(const float* __restrict__ x,
                                               unsigned short* __restrict__ xb) {
    const int stride = gridDim.x * 256;
    const int n4 = N_PAD * F_IN / 4;
    const int nv = N_NODES * F_IN / 4;
    for (int i = blockIdx.x * 256 + threadIdx.x; i < n4; i += stride) {
        us4 o;
        if (i < nv) {
            float4 v = *(const float4*)(x + (size_t)i * 4);
            o.x = f2bf(v.x); o.y = f2bf(v.y); o.z = f2bf(v.z); o.w = f2bf(v.w);
        } else {
            o.x = 0; o.y = 0; o.z = 0; o.w = 0;
        }
        *(us4*)(xb + (size_t)i * 4) = o;
    }
}

// ---------- graph build ----------

__global__ void hist_k(const void* ei, const int* flag, int* cnt, long long E) {
    long long e = (long long)blockIdx.x * 256 + threadIdx.x;
    if (e >= E) return;
    int d = eidx(ei, E + e, *flag);
    atomicAdd(&cnt[d], 1);
}

__global__ __launch_bounds__(512) void scan1_k(const int* cnt, int* rowoff, int* bsum,
                                               float* dinv, int n) {
    __shared__ int s[512];
    int t = threadIdx.x;
    int i = blockIdx.x * 512 + t;
    int v = (i < n) ? cnt[i] : 0;
    s[t] = v;
    __syncthreads();
    for (int off = 1; off < 512; off <<= 1) {
        int add = (t >= off) ? s[t - off] : 0;
        __syncthreads();
        s[t] += add;
        __syncthreads();
    }
    if (i < n) {
        rowoff[i] = s[t] - v;
        dinv[i] = rsqrtf((float)(v + 1));
    }
    if (t == 511) bsum[blockIdx.x] = s[511];
}

__global__ void scan2_k(int* bsum, int nb) {
    __shared__ int s[128];
    int t = threadIdx.x;
    int v = (t < nb) ? bsum[t] : 0;
    s[t] = v;
    __syncthreads();
    for (int off = 1; off < 128; off <<= 1) {
        int add = (t >= off) ? s[t - off] : 0;
        __syncthreads();
        s[t] += add;
        __syncthreads();
    }
    if (t < nb) bsum[t] = s[t] - v;
}

__global__ __launch_bounds__(512) void scan3_k(int* rowoff, const int* bsum, int n, int total) {
    int i = blockIdx.x * 512 + threadIdx.x;
    if (i < n) rowoff[i] += bsum[blockIdx.x];
    if (i == 0) rowoff[n] = total;
}

__global__ void scatter_k(const void* ei, const int* flag, const float* dinv,
                          const int* rowoff, int* cur, long long E, int2* colnorm) {
    long long e = (long long)blockIdx.x * 256 + threadIdx.x;
    if (e >= E) return;
    int is64 = *flag;
    int s = eidx(ei, e, is64);
    int d = eidx(ei, E + e, is64);
    int pos = rowoff[d] + atomicAdd(&cur[d], 1);
    float nrm = dinv[s] * dinv[d];
    int2 cn;
    cn.x = s;
    cn.y = __float_as_int(nrm);
    colnorm[pos] = cn;
}

// ---------- GEMM1: h1 = bf16(xb @ W1), global_load_lds pipeline (r6) ------

__global__ __launch_bounds__(512, 4) void gemm1_k(const unsigned short* __restrict__ xb,
                                                  const unsigned short* __restrict__ w1t,
                                                  unsigned short* __restrict__ h1) {
    __shared__ __align__(16) unsigned short As[2][128 * 32];   // 16 KB
    __shared__ __align__(16) unsigned short Bs[2][256 * 32];   // 32 KB

    const int t = threadIdx.x;
    const int wv = t >> 6, lane = t & 63;
    const int lg = lane >> 4, lr = lane & 15;
    const int wm = wv >> 2, wn = wv & 3;

    const size_t arow = (size_t)blockIdx.x * 128 + (t >> 2);
    const unsigned short* asrc = xb + arow * F_IN + (t & 3) * 8;
    const unsigned short* bsrc0 = w1t + (size_t)(t >> 2) * F_IN + (t & 3) * 8;
    const unsigned short* bsrc1 = bsrc0 + 128 * F_IN;

#define STAGE(bf, ks)                                                         \
    do { const int _o = (ks) * 32;                                            \
        GLOAD16(asrc + _o, &As[bf][t * 8]);                                   \
        GLOAD16(bsrc0 + _o, &Bs[bf][t * 8]);                                  \
        GLOAD16(bsrc1 + _o, &Bs[bf][(t + 512) * 8]);                          \
    } while (0)

    f32x4 acc[4][4] = {};

    STAGE(0, 0);
    __syncthreads();

    for (int ks = 0; ks < 16; ++ks) {
        const int bf = ks & 1;
        if (ks < 15) STAGE(bf ^ 1, ks + 1);
        short8 afr[4], bfr[4];
#pragma unroll
        for (int mi = 0; mi < 4; ++mi)
            afr[mi] = *(const short8*)&As[bf][(wm * 64 + mi * 16 + lr) * 32 + lg * 8];
#pragma unroll
        for (int ni = 0; ni < 4; ++ni)
            bfr[ni] = *(const short8*)&Bs[bf][(wn * 64 + ni * 16 + lr) * 32 + lg * 8];
#pragma unroll
        for (int mi = 0; mi < 4; ++mi)
#pragma unroll
            for (int ni = 0; ni < 4; ++ni)
                acc[mi][ni] = __builtin_amdgcn_mfma_f32_16x16x32_bf16(
                    afr[mi], bfr[ni], acc[mi][ni], 0, 0, 0);
        __syncthreads();
    }
#undef STAGE

    const size_t rbase = (size_t)blockIdx.x * 128 + wm * 64 + lg * 4;
#pragma unroll
    for (int mi = 0; mi < 4; ++mi)
#pragma unroll
        for (int ni = 0; ni < 4; ++ni)
#pragma unroll
            for (int j = 0; j < 4; ++j)
                h1[(rbase + mi * 16 + j) * H_DIM + wn * 64 + ni * 16 + lr] =
                    f2bf(acc[mi][ni][j]);
}

// ---------- Aggregation layer 1, XCD cache-partitioned ----------
// blockIdx%8 = feature slice (32 feats = 64B). Under round-robin block->XCD
// dispatch, XCD s only touches h1[:, 32s:32s+32] = 3.2MB -> L2-resident.
// 16-lane groups gather 64B/edge; 4 nodes per wave; 4-deep edge ILP.

__global__ __launch_bounds__(256) void agg1_k(const unsigned short* __restrict__ h1,
                                              const int* __restrict__ rowoff,
                                              const int2* __restrict__ colnorm,
                                              const float* __restrict__ dinv,
                                              const float* __restrict__ b1,
                                              unsigned short* __restrict__ h1a) {
    const int slice = blockIdx.x & 7;
    const int nb = blockIdx.x >> 3;
    const int grp = threadIdx.x >> 4;       // 0..15
    const int li = threadIdx.x & 15;
    const int node = nb * 16 + grp;
    if (node >= N_NODES) return;
    const int f = slice * 32 + li * 2;
    const unsigned short* base = h1 + f;
    const int beg = rowoff[node], end = rowoff[node + 1];
    float a0 = 0.f, a1 = 0.f;

    int e = beg;
    for (; e + 3 < end; e += 4) {
        int2 c0 = colnorm[e];
        int2 c1 = colnorm[e + 1];
        int2 c2 = colnorm[e + 2];
        int2 c3 = colnorm[e + 3];
        uint32_t v0 = *(const uint32_t*)(base + (size_t)c0.x * H_DIM);
        uint32_t v1 = *(const uint32_t*)(base + (size_t)c1.x * H_DIM);
        uint32_t v2 = *(const uint32_t*)(base + (size_t)c2.x * H_DIM);
        uint32_t v3 = *(const uint32_t*)(base + (size_t)c3.x * H_DIM);
        float n0 = __int_as_float(c0.y), n1 = __int_as_float(c1.y);
        float n2 = __int_as_float(c2.y), n3 = __int_as_float(c3.y);
        a0 += n0 * bf2f(v0 & 0xffff) + n1 * bf2f(v1 & 0xffff)
            + n2 * bf2f(v2 & 0xffff) + n3 * bf2f(v3 & 0xffff);
        a1 += n0 * bf2f(v0 >> 16) + n1 * bf2f(v1 >> 16)
            + n2 * bf2f(v2 >> 16) + n3 * bf2f(v3 >> 16);
    }
    for (; e < end; ++e) {
        int2 c0 = colnorm[e];
        uint32_t v0 = *(const uint32_t*)(base + (size_t)c0.x * H_DIM);
        float n0 = __int_as_float(c0.y);
        a0 += n0 * bf2f(v0 & 0xffff);
        a1 += n0 * bf2f(v0 >> 16);
    }
    // self loop
    float dn = dinv[node];
    float sn = dn * dn;
    uint32_t vs = *(const uint32_t*)(base + (size_t)node * H_DIM);
    a0 += sn * bf2f(vs & 0xffff);
    a1 += sn * bf2f(vs >> 16);
    // bias + relu
    float2 bb = *(const float2*)(b1 + f);
    a0 = fmaxf(a0 + bb.x, 0.f);
    a1 = fmaxf(a1 + bb.y, 0.f);
    uint32_t o = (uint32_t)f2bf(a0) | ((uint32_t)f2bf(a1) << 16);
    *(uint32_t*)(h1a + (size_t)node * H_DIM + f) = o;
}

// ---------- GEMM2: h2[50000x16] = h1a @ W2 (MFMA straight from global) ----

__global__ __launch_bounds__(256) void gemm2_k(const unsigned short* __restrict__ h1a,
                                               const unsigned short* __restrict__ w2t,
                                               float* __restrict__ h2) {
    int t = threadIdx.x;
    int wv = t >> 6, lane = t & 63, lg = lane >> 4, lr = lane & 15;
    int rbase = blockIdx.x * 64 + wv * 16;
    int rr = rbase + lr;
    int rc = rr < N_NODES ? rr : N_NODES - 1;
    f32x4 acc = {0.f, 0.f, 0.f, 0.f};
#pragma unroll
    for (int ks = 0; ks < 8; ++ks) {
        short8 a = *(const short8*)(h1a + (long long)rc * H_DIM + ks * 32 + lg * 8);
        short8 b = *(const short8*)(w2t + lr * H_DIM + ks * 32 + lg * 8);
        acc = __builtin_amdgcn_mfma_f32_16x16x32_bf16(a, b, acc, 0, 0, 0);
    }
#pragma unroll
    for (int j = 0; j < 4; ++j) {
        int row = rbase + lg * 4 + j;
        if (row < N_NODES) h2[(long long)row * C_DIM + lr] = acc[j];
    }
}

// ---------- Aggregation layer 2: out = A_norm @ h2 + b2 (fp32) ----------

__global__ __launch_bounds__(256) void agg2_k(const float* __restrict__ h2,
                                              const int* __restrict__ rowoff,
                                              const int2* __restrict__ colnorm,
                                              const float* __restrict__ dinv,
                                              const float* __restrict__ b2,
                                              float* __restrict__ out) {
    int g = threadIdx.x >> 4, c = threadIdx.x & 15;
    int node = blockIdx.x * 16 + g;
    if (node >= N_NODES) return;
    int beg = rowoff[node], end = rowoff[node + 1];
    float acc = 0.f;
    int e = beg;
    for (; e + 1 < end; e += 2) {
        int2 cn0 = colnorm[e];
        int2 cn1 = colnorm[e + 1];
        acc += __int_as_float(cn0.y) * h2[(long long)cn0.x * C_DIM + c]
             + __int_as_float(cn1.y) * h2[(long long)cn1.x * C_DIM + c];
    }
    if (e < end) {
        int2 cn = colnorm[e];
        acc += __int_as_float(cn.y) * h2[(long long)cn.x * C_DIM + c];
    }
    float dn = dinv[node];
    acc += dn * dn * h2[(long long)node * C_DIM + c];
    out[(long long)node * C_DIM + c] = acc + b2[c];
}

// ---------- launch ----------

extern "C" void kernel_launch(void* const* d_in, const int* in_sizes, int n_in,
                              void* d_out, int out_size, void* d_ws, size_t ws_size,
                              hipStream_t stream) {
    const float* x  = (const float*)d_in[0];
    const void*  ei = d_in[1];
    const float* W1 = (const float*)d_in[2];
    const float* b1 = (const float*)d_in[3];
    const float* W2 = (const float*)d_in[4];
    const float* b2 = (const float*)d_in[5];
    float* out = (float*)d_out;
    long long E = (long long)in_sizes[1] / 2;

    char* w = (char*)d_ws;
    auto alloc = [&](size_t bytes) -> char* {
        char* p = w;
        w += (bytes + 255) & ~(size_t)255;
        return p;
    };
    int*   flag    = (int*)   alloc(4);
    int*   cnt     = (int*)   alloc((size_t)N_NODES * 4);
    int*   cur     = (int*)   alloc((size_t)N_NODES * 4);
    float* dinv    = (float*) alloc((size_t)N_NODES * 4);
    int*   rowoff  = (int*)   alloc((size_t)(N_NODES + 1) * 4);
    int*   bsum    = (int*)   alloc(512 * 4);
    int2*  colnorm = (int2*)  alloc((size_t)E * 8);
    unsigned short* w1t = (unsigned short*)alloc((size_t)H_DIM * F_IN * 2);
    unsigned short* w2t = (unsigned short*)alloc((size_t)C_DIM * H_DIM * 2);
    unsigned short* xb  = (unsigned short*)alloc((size_t)N_PAD * F_IN * 2);  // 51.25 MB
    unsigned short* h1  = (unsigned short*)alloc((size_t)N_PAD * H_DIM * 2); // 25.6 MB
    float* h2 = (float*)alloc((size_t)N_NODES * C_DIM * 4);
    unsigned short* h1a = xb;   // xb dead after gemm1 -> overlay

    prep_k<<<(F_IN * H_DIM + 255) / 256, 256, 0, stream>>>(ei, flag, W1, w1t, W2, w2t,
                                                           cnt, cur);
    xconv_k<<<2048, 256, 0, stream>>>(x, xb);

    int egrid = (int)((E + 255) / 256);
    hist_k<<<egrid, 256, 0, stream>>>(ei, flag, cnt, E);
    int sgrid = (N_NODES + 511) / 512;
    scan1_k<<<sgrid, 512, 0, stream>>>(cnt, rowoff, bsum, dinv, N_NODES);
    scan2_k<<<1, 128, 0, stream>>>(bsum, sgrid);
    scan3_k<<<sgrid, 512, 0, stream>>>(rowoff, bsum, N_NODES, (int)E);
    scatter_k<<<egrid, 256, 0, stream>>>(ei, flag, dinv, rowoff, cur, E, colnorm);

    gemm1_k<<<N_PAD / 128, 512, 0, stream>>>(xb, w1t, h1);
    agg1_k<<<8 * ((N_NODES + 15) / 16), 256, 0, stream>>>(h1, rowoff, colnorm, dinv,
                                                          b1, h1a);
    gemm2_k<<<(N_NODES + 63) / 64, 256, 0, stream>>>(h1a, w2t, h2);
    agg2_k<<<(N_NODES + 15) / 16, 256, 0, stream>>>(h2, rowoff, colnorm, dinv, b2, out);
}

// Round 8
// 210.692 us; speedup vs baseline: 1.2396x; 1.2396x over previous
//
#include <hip/hip_runtime.h>
#include <stdint.h>

#define N_NODES 50000
#define N_PAD   50048     // 391 * 128
#define F_IN 512
#define H_DIM 256
#define C_DIM 16

typedef __attribute__((ext_vector_type(8))) short short8;
typedef __attribute__((ext_vector_type(4))) float f32x4;
typedef __attribute__((ext_vector_type(4))) unsigned short us4;
typedef __attribute__((ext_vector_type(8))) unsigned short us8;

__device__ inline float bf2f(unsigned short u) {
    return __uint_as_float(((uint32_t)u) << 16);
}
__device__ inline unsigned short f2bf(float f) {
    uint32_t u = __float_as_uint(f);
    u += 0x7FFFu + ((u >> 16) & 1u);   // round-to-nearest-even
    return (unsigned short)(u >> 16);
}
__device__ inline unsigned short hx(float f) {   // truncating bf16 (1 op)
    return (unsigned short)(__float_as_uint(f) >> 16);
}
__device__ inline int eidx(const void* p, long long i, int is64) {
    return is64 ? (int)((const long long*)p)[i] : ((const int*)p)[i];
}

// async global->LDS, 16B per lane, linear LDS dest (wave base + lane*16)
#define GLOAD16(gp, lp)                                                       \
    __builtin_amdgcn_global_load_lds(                                         \
        (const __attribute__((address_space(1))) void*)(gp),                  \
        (__attribute__((address_space(3))) void*)(lp), 16, 0, 0)

// ---------- fused prep: dtype detect + W transpose-convert + cnt/cur zero --

__global__ void prep_k(const void* ei, int* flag,
                       const float* w1, unsigned short* w1t,
                       const float* w2, unsigned short* w2t,
                       int* cnt, int* cur) {
    int i = blockIdx.x * 256 + threadIdx.x;
    if (i == 0) {
        const uint32_t* w = (const uint32_t*)ei;
        int is64 = 1;
        for (int j = 1; j < 128; j += 2)
            if (w[j] != 0u) { is64 = 0; break; }
        *flag = is64;
    }
    if (i < N_NODES) { cnt[i] = 0; cur[i] = 0; }
    if (i < F_IN * H_DIM) {
        int k = i / H_DIM, n = i % H_DIM;
        w1t[n * F_IN + k] = f2bf(w1[i]);
    }
    if (i < H_DIM * C_DIM) {
        int k = i / C_DIM, n = i % C_DIM;
        w2t[n * H_DIM + k] = f2bf(w2[i]);
    }
}

// ---------- graph build ----------

__global__ void hist_k(const void* ei, const int* flag, int* cnt, long long E) {
    long long e = (long long)blockIdx.x * 256 + threadIdx.x;
    if (e >= E) return;
    int d = eidx(ei, E + e, *flag);
    atomicAdd(&cnt[d], 1);
}

__global__ __launch_bounds__(512) void scan1_k(const int* cnt, int* rowoff, int* bsum,
                                               float* dinv, int n) {
    __shared__ int s[512];
    int t = threadIdx.x;
    int i = blockIdx.x * 512 + t;
    int v = (i < n) ? cnt[i] : 0;
    s[t] = v;
    __syncthreads();
    for (int off = 1; off < 512; off <<= 1) {
        int add = (t >= off) ? s[t - off] : 0;
        __syncthreads();
        s[t] += add;
        __syncthreads();
    }
    if (i < n) {
        rowoff[i] = s[t] - v;
        dinv[i] = rsqrtf((float)(v + 1));
    }
    if (t == 511) bsum[blockIdx.x] = s[511];
}

__global__ void scan2_k(int* bsum, int nb) {
    __shared__ int s[128];
    int t = threadIdx.x;
    int v = (t < nb) ? bsum[t] : 0;
    s[t] = v;
    __syncthreads();
    for (int off = 1; off < 128; off <<= 1) {
        int add = (t >= off) ? s[t - off] : 0;
        __syncthreads();
        s[t] += add;
        __syncthreads();
    }
    if (t < nb) bsum[t] = s[t] - v;
}

__global__ __launch_bounds__(512) void scan3_k(int* rowoff, const int* bsum, int n, int total) {
    int i = blockIdx.x * 512 + threadIdx.x;
    if (i < n) rowoff[i] += bsum[blockIdx.x];
    if (i == 0) rowoff[n] = total;
}

__global__ void scatter_k(const void* ei, const int* flag, const float* dinv,
                          const int* rowoff, int* cur, long long E, int2* colnorm) {
    long long e = (long long)blockIdx.x * 256 + threadIdx.x;
    if (e >= E) return;
    int is64 = *flag;
    int s = eidx(ei, e, is64);
    int d = eidx(ei, E + e, is64);
    int pos = rowoff[d] + atomicAdd(&cur[d], 1);
    float nrm = dinv[s] * dinv[d];
    int2 cn;
    cn.x = s;
    cn.y = __float_as_int(nrm);
    colnorm[pos] = cn;
}

// ---------- GEMM1: h1 = bf16(x @ W1), fp32-A global_load_lds pipeline ------
// Tile 128M x 256N, BK=32, 8 waves (2Mx4N), acc[4][4], grid 391.
// A staged as RAW FP32 via global_load_lds (no xconv pass, x read once);
// fp32->bf16 truncation at fragment read (1 op/elem, hidden under mem-bound).
// A LDS uses chunk-XOR swizzle applied on the GLOBAL source address (rule:
// linear gload dest + inverse-swizzled source + swizzled read); same 128B
// line set per wave -> coalescing unchanged. B bf16 linear as r6.
// Tail block: source rows clamped to 49999 (garbage -> h1 pad rows only).

__global__ __launch_bounds__(512, 4) void gemm1_k(const float* __restrict__ x,
                                                  const unsigned short* __restrict__ w1t,
                                                  unsigned short* __restrict__ h1) {
    __shared__ __align__(16) float          Asf[2][128 * 32];  // 32 KB
    __shared__ __align__(16) unsigned short Bs[2][256 * 32];   // 32 KB

    const int t = threadIdx.x;
    const int wv = t >> 6, lane = t & 63;
    const int lg = lane >> 4, lr = lane & 15;
    const int wm = wv >> 2, wn = wv & 3;

    // A stage: thread covers rows (t>>3) and (t>>3)+64, 16B chunk (t&7),
    // source chunk pre-swizzled by row&7 ((row+64)&7 == row&7).
    const int arow0 = t >> 3;
    const int achk = (t & 7) ^ (arow0 & 7);
    size_t g0 = (size_t)blockIdx.x * 128 + arow0;
    size_t g1 = g0 + 64;
    if (g0 > N_NODES - 1) g0 = N_NODES - 1;
    if (g1 > N_NODES - 1) g1 = N_NODES - 1;
    const float* asrc0 = x + g0 * F_IN + achk * 4;
    const float* asrc1 = x + g1 * F_IN + achk * 4;
    // B stage: as r6
    const unsigned short* bsrc0 = w1t + (size_t)(t >> 2) * F_IN + (t & 3) * 8;
    const unsigned short* bsrc1 = bsrc0 + 128 * F_IN;

#define STAGE(bf, ks)                                                         \
    do { const int _o = (ks) * 32;                                            \
        GLOAD16(asrc0 + _o, &Asf[bf][t * 4]);                                 \
        GLOAD16(asrc1 + _o, &Asf[bf][t * 4 + 2048]);                          \
        GLOAD16(bsrc0 + _o, &Bs[bf][t * 8]);                                  \
        GLOAD16(bsrc1 + _o, &Bs[bf][(t + 512) * 8]);                          \
    } while (0)

    f32x4 acc[4][4] = {};

    STAGE(0, 0);
    __syncthreads();

    for (int ks = 0; ks < 16; ++ks) {
        const int bf = ks & 1;
        if (ks < 15) STAGE(bf ^ 1, ks + 1);
        short8 afr[4], bfr[4];
#pragma unroll
        for (int mi = 0; mi < 4; ++mi) {
            const int r = wm * 64 + mi * 16 + lr;
            const int s = r & 7;
            const float* base = &Asf[bf][r * 32];
            f32x4 lo = *(const f32x4*)(base + (((lg * 2) ^ s) * 4));
            f32x4 hi = *(const f32x4*)(base + (((lg * 2 + 1) ^ s) * 4));
            short8 a;
            a[0] = (short)hx(lo[0]); a[1] = (short)hx(lo[1]);
            a[2] = (short)hx(lo[2]); a[3] = (short)hx(lo[3]);
            a[4] = (short)hx(hi[0]); a[5] = (short)hx(hi[1]);
            a[6] = (short)hx(hi[2]); a[7] = (short)hx(hi[3]);
            afr[mi] = a;
        }
#pragma unroll
        for (int ni = 0; ni < 4; ++ni)
            bfr[ni] = *(const short8*)&Bs[bf][(wn * 64 + ni * 16 + lr) * 32 + lg * 8];
#pragma unroll
        for (int mi = 0; mi < 4; ++mi)
#pragma unroll
            for (int ni = 0; ni < 4; ++ni)
                acc[mi][ni] = __builtin_amdgcn_mfma_f32_16x16x32_bf16(
                    afr[mi], bfr[ni], acc[mi][ni], 0, 0, 0);
        __syncthreads();
    }
#undef STAGE

    // C layout: col=lane&15, row=(lane>>4)*4+reg; h1 padded -> no guards
    const size_t rbase = (size_t)blockIdx.x * 128 + wm * 64 + lg * 4;
#pragma unroll
    for (int mi = 0; mi < 4; ++mi)
#pragma unroll
        for (int ni = 0; ni < 4; ++ni)
#pragma unroll
            for (int j = 0; j < 4; ++j)
                h1[(rbase + mi * 16 + j) * H_DIM + wn * 64 + ni * 16 + lr] =
                    f2bf(acc[mi][ni][j]);
}

// ---------- Aggregation layer 1 (r6 form): h1a = bf16(relu(Anorm@h1+b1)) ---
// 1 wave per dst node; half-wave (32 lanes x us8 = full 512B row) per edge;
// halves process even/odd edges (4-deep ILP), combined by shfl_xor(32).

__global__ __launch_bounds__(256) void agg1_k(const unsigned short* __restrict__ h1,
                                              const int* __restrict__ rowoff,
                                              const int2* __restrict__ colnorm,
                                              const float* __restrict__ dinv,
                                              const float* __restrict__ b1,
                                              unsigned short* __restrict__ h1a) {
    int wv = threadIdx.x >> 6, lane = threadIdx.x & 63;
    int node = blockIdx.x * 4 + wv;
    if (node >= N_NODES) return;
    int half = lane >> 5;
    int fl = (lane & 31) * 8;
    int beg = rowoff[node], end = rowoff[node + 1];
    float a[8] = {0.f, 0.f, 0.f, 0.f, 0.f, 0.f, 0.f, 0.f};
    const unsigned short* base = h1 + fl;

    int e = beg + half;
    while (e + 6 < end) {
        int2 c[4];
        us8 v[4];
#pragma unroll
        for (int q = 0; q < 4; ++q) c[q] = colnorm[e + q * 2];
#pragma unroll
        for (int q = 0; q < 4; ++q)
            v[q] = *(const us8*)(base + (long long)c[q].x * H_DIM);
#pragma unroll
        for (int q = 0; q < 4; ++q) {
            float n = __int_as_float(c[q].y);
#pragma unroll
            for (int j = 0; j < 8; ++j) a[j] += n * bf2f(v[q][j]);
        }
        e += 8;
    }
    while (e < end) {
        int2 c0 = colnorm[e];
        us8 v0 = *(const us8*)(base + (long long)c0.x * H_DIM);
        float n0 = __int_as_float(c0.y);
#pragma unroll
        for (int j = 0; j < 8; ++j) a[j] += n0 * bf2f(v0[j]);
        e += 2;
    }
#pragma unroll
    for (int j = 0; j < 8; ++j)
        a[j] += __shfl_xor(a[j], 32);

    if (half == 0) {
        float dn = dinv[node];
        float sn = dn * dn;
        us8 vs = *(const us8*)(base + (long long)node * H_DIM);
        float4 b0 = *(const float4*)(b1 + fl);
        float4 b4 = *(const float4*)(b1 + fl + 4);
        float bb[8] = {b0.x, b0.y, b0.z, b0.w, b4.x, b4.y, b4.z, b4.w};
        us8 o;
#pragma unroll
        for (int j = 0; j < 8; ++j) {
            float r = fmaxf(a[j] + sn * bf2f(vs[j]) + bb[j], 0.f);
            o[j] = f2bf(r);
        }
        *(us8*)(h1a + (long long)node * H_DIM + fl) = o;
    }
}

// ---------- GEMM2: h2[50000x16] = h1a @ W2 (MFMA straight from global) ----

__global__ __launch_bounds__(256) void gemm2_k(const unsigned short* __restrict__ h1a,
                                               const unsigned short* __restrict__ w2t,
                                               float* __restrict__ h2) {
    int t = threadIdx.x;
    int wv = t >> 6, lane = t & 63, lg = lane >> 4, lr = lane & 15;
    int rbase = blockIdx.x * 64 + wv * 16;
    int rr = rbase + lr;
    int rc = rr < N_NODES ? rr : N_NODES - 1;
    f32x4 acc = {0.f, 0.f, 0.f, 0.f};
#pragma unroll
    for (int ks = 0; ks < 8; ++ks) {
        short8 a = *(const short8*)(h1a + (long long)rc * H_DIM + ks * 32 + lg * 8);
        short8 b = *(const short8*)(w2t + lr * H_DIM + ks * 32 + lg * 8);
        acc = __builtin_amdgcn_mfma_f32_16x16x32_bf16(a, b, acc, 0, 0, 0);
    }
#pragma unroll
    for (int j = 0; j < 4; ++j) {
        int row = rbase + lg * 4 + j;
        if (row < N_NODES) h2[(long long)row * C_DIM + lr] = acc[j];
    }
}

// ---------- Aggregation layer 2: out = A_norm @ h2 + b2 (fp32) ----------

__global__ __launch_bounds__(256) void agg2_k(const float* __restrict__ h2,
                                              const int* __restrict__ rowoff,
                                              const int2* __restrict__ colnorm,
                                              const float* __restrict__ dinv,
                                              const float* __restrict__ b2,
                                              float* __restrict__ out) {
    int g = threadIdx.x >> 4, c = threadIdx.x & 15;
    int node = blockIdx.x * 16 + g;
    if (node >= N_NODES) return;
    int beg = rowoff[node], end = rowoff[node + 1];
    float acc = 0.f;
    int e = beg;
    for (; e + 1 < end; e += 2) {
        int2 cn0 = colnorm[e];
        int2 cn1 = colnorm[e + 1];
        acc += __int_as_float(cn0.y) * h2[(long long)cn0.x * C_DIM + c]
             + __int_as_float(cn1.y) * h2[(long long)cn1.x * C_DIM + c];
    }
    if (e < end) {
        int2 cn = colnorm[e];
        acc += __int_as_float(cn.y) * h2[(long long)cn.x * C_DIM + c];
    }
    float dn = dinv[node];
    acc += dn * dn * h2[(long long)node * C_DIM + c];
    out[(long long)node * C_DIM + c] = acc + b2[c];
}

// ---------- launch ----------

extern "C" void kernel_launch(void* const* d_in, const int* in_sizes, int n_in,
                              void* d_out, int out_size, void* d_ws, size_t ws_size,
                              hipStream_t stream) {
    const float* x  = (const float*)d_in[0];
    const void*  ei = d_in[1];
    const float* W1 = (const float*)d_in[2];
    const float* b1 = (const float*)d_in[3];
    const float* W2 = (const float*)d_in[4];
    const float* b2 = (const float*)d_in[5];
    float* out = (float*)d_out;
    long long E = (long long)in_sizes[1] / 2;

    char* w = (char*)d_ws;
    auto alloc = [&](size_t bytes) -> char* {
        char* p = w;
        w += (bytes + 255) & ~(size_t)255;
        return p;
    };
    int*   flag    = (int*)   alloc(4);
    int*   cnt     = (int*)   alloc((size_t)N_NODES * 4);
    int*   cur     = (int*)   alloc((size_t)N_NODES * 4);
    float* dinv    = (float*) alloc((size_t)N_NODES * 4);
    int*   rowoff  = (int*)   alloc((size_t)(N_NODES + 1) * 4);
    int*   bsum    = (int*)   alloc(512 * 4);
    int2*  colnorm = (int2*)  alloc((size_t)E * 8);
    unsigned short* w1t = (unsigned short*)alloc((size_t)H_DIM * F_IN * 2);
    unsigned short* w2t = (unsigned short*)alloc((size_t)C_DIM * H_DIM * 2);
    unsigned short* h1  = (unsigned short*)alloc((size_t)N_PAD * H_DIM * 2);   // 25.6 MB
    unsigned short* h1a = (unsigned short*)alloc((size_t)N_NODES * H_DIM * 2); // 25.6 MB
    float* h2 = (float*)alloc((size_t)N_NODES * C_DIM * 4);

    prep_k<<<(F_IN * H_DIM + 255) / 256, 256, 0, stream>>>(ei, flag, W1, w1t, W2, w2t,
                                                           cnt, cur);

    int egrid = (int)((E + 255) / 256);
    hist_k<<<egrid, 256, 0, stream>>>(ei, flag, cnt, E);
    int sgrid = (N_NODES + 511) / 512;
    scan1_k<<<sgrid, 512, 0, stream>>>(cnt, rowoff, bsum, dinv, N_NODES);
    scan2_k<<<1, 128, 0, stream>>>(bsum, sgrid);
    scan3_k<<<sgrid, 512, 0, stream>>>(rowoff, bsum, N_NODES, (int)E);
    scatter_k<<<egrid, 256, 0, stream>>>(ei, flag, dinv, rowoff, cur, E, colnorm);

    gemm1_k<<<N_PAD / 128, 512, 0, stream>>>(x, w1t, h1);
    agg1_k<<<(N_NODES + 3) / 4, 256, 0, stream>>>(h1, rowoff, colnorm, dinv, b1, h1a);
    gemm2_k<<<(N_NODES + 63) / 64, 256, 0, stream>>>(h1a, w2t, h2);
    agg2_k<<<(N_NODES + 15) / 16, 256, 0, stream>>>(h2, rowoff, colnorm, dinv, b2, out);
}

// Round 9
// 202.219 us; speedup vs baseline: 1.2916x; 1.0419x over previous
//
#include <hip/hip_runtime.h>
#include <stdint.h>

#define N_NODES 50000
#define N_PAD   50048     // 391 * 128
#define F_IN 512
#define H_DIM 256
#define C_DIM 16

typedef __attribute__((ext_vector_type(8))) short short8;
typedef __attribute__((ext_vector_type(4))) float f32x4;
typedef __attribute__((ext_vector_type(4))) unsigned short us4;
typedef __attribute__((ext_vector_type(8))) unsigned short us8;

__device__ inline float bf2f(unsigned short u) {
    return __uint_as_float(((uint32_t)u) << 16);
}
__device__ inline unsigned short f2bf(float f) {
    uint32_t u = __float_as_uint(f);
    u += 0x7FFFu + ((u >> 16) & 1u);   // round-to-nearest-even
    return (unsigned short)(u >> 16);
}
__device__ inline unsigned short hx(float f) {   // truncating bf16 (1 op)
    return (unsigned short)(__float_as_uint(f) >> 16);
}
__device__ inline int eidx(const void* p, long long i, int is64) {
    return is64 ? (int)((const long long*)p)[i] : ((const int*)p)[i];
}

// CSR row bounds WITHOUT scan3: rowoff holds per-512-chunk exclusive sums,
// bsum holds exclusive chunk offsets (scan2 output).
__device__ inline int row_beg(const int* ro, const int* bs, int n) {
    return ro[n] + bs[n >> 9];
}
__device__ inline int row_end(const int* ro, const int* bs, int n, int E) {
    return (n + 1 < N_NODES) ? ro[n + 1] + bs[(n + 1) >> 9] : E;
}

// async global->LDS, 16B per lane, linear LDS dest (wave base + lane*16)
#define GLOAD16(gp, lp)                                                       \
    __builtin_amdgcn_global_load_lds(                                         \
        (const __attribute__((address_space(1))) void*)(gp),                  \
        (__attribute__((address_space(3))) void*)(lp), 16, 0, 0)

// ---------- fused prep: dtype detect + W transpose-convert + cnt/cur zero --

__global__ void prep_k(const void* ei, int* flag,
                       const float* w1, unsigned short* w1t,
                       const float* w2, unsigned short* w2t,
                       int* cnt, int* cur) {
    int i = blockIdx.x * 256 + threadIdx.x;
    if (i == 0) {
        const uint32_t* w = (const uint32_t*)ei;
        int is64 = 1;
        for (int j = 1; j < 128; j += 2)
            if (w[j] != 0u) { is64 = 0; break; }
        *flag = is64;
    }
    if (i < N_NODES) { cnt[i] = 0; cur[i] = 0; }
    if (i < F_IN * H_DIM) {
        int k = i / H_DIM, n = i % H_DIM;
        w1t[n * F_IN + k] = f2bf(w1[i]);
    }
    if (i < H_DIM * C_DIM) {
        int k = i / C_DIM, n = i % C_DIM;
        w2t[n * H_DIM + k] = f2bf(w2[i]);
    }
}

// ---------- graph build ----------

__global__ void hist_k(const void* ei, const int* flag, int* cnt, long long E) {
    long long e = (long long)blockIdx.x * 256 + threadIdx.x;
    if (e >= E) return;
    int d = eidx(ei, E + e, *flag);
    atomicAdd(&cnt[d], 1);
}

__global__ __launch_bounds__(512) void scan1_k(const int* cnt, int* rowoff, int* bsum,
                                               float* dinv, int n) {
    __shared__ int s[512];
    int t = threadIdx.x;
    int i = blockIdx.x * 512 + t;
    int v = (i < n) ? cnt[i] : 0;
    s[t] = v;
    __syncthreads();
    for (int off = 1; off < 512; off <<= 1) {
        int add = (t >= off) ? s[t - off] : 0;
        __syncthreads();
        s[t] += add;
        __syncthreads();
    }
    if (i < n) {
        rowoff[i] = s[t] - v;                 // exclusive within chunk
        dinv[i] = rsqrtf((float)(v + 1));
    }
    if (t == 511) bsum[blockIdx.x] = s[511];
}

__global__ void scan2_k(int* bsum, int nb) {
    __shared__ int s[128];
    int t = threadIdx.x;
    int v = (t < nb) ? bsum[t] : 0;
    s[t] = v;
    __syncthreads();
    for (int off = 1; off < 128; off <<= 1) {
        int add = (t >= off) ? s[t - off] : 0;
        __syncthreads();
        s[t] += add;
        __syncthreads();
    }
    if (t < nb) bsum[t] = s[t] - v;     // exclusive chunk offsets
}

__global__ void scatter_k(const void* ei, const int* flag, const float* dinv,
                          const int* rowoff, const int* bsum, int* cur,
                          long long E, int2* colnorm) {
    long long e = (long long)blockIdx.x * 256 + threadIdx.x;
    if (e >= E) return;
    int is64 = *flag;
    int s = eidx(ei, e, is64);
    int d = eidx(ei, E + e, is64);
    int pos = row_beg(rowoff, bsum, d) + atomicAdd(&cur[d], 1);
    float nrm = dinv[s] * dinv[d];
    int2 cn;
    cn.x = s;
    cn.y = __float_as_int(nrm);
    colnorm[pos] = cn;
}

// ---------- GEMM1: h1 = bf16(x @ W1), fp32-A gload_lds + counted-vmcnt -----
// Tile 128M x 256N, BK=32, 8 waves (2Mx4N), acc[4][4], grid 391 (resident,
// 2 blocks/CU). Per K-step: STAGE(k+1) [4 DMA loads/thread]; vmcnt(4) drains
// ONLY the older buf-k loads (buf-k+1's stay in flight through the MFMAs);
// bar1 makes buf-k cross-wave visible; COMPUTE(k); bar2 protects the buffer
// STAGE(k+2) will overwrite. Hazards: (a) overwrite - STAGE(i+1) writes the
// buffer last read at COMPUTE(i-1), separated by bar2(i-1); (b) readiness -
// buf-i's 4 loads are the oldest of the <=8 outstanding at vmcnt(4).
// A staged as RAW FP32 (x read once, no xconv); fp32->bf16 truncation at
// fragment read. A-LDS chunk-XOR swizzle applied on the GLOBAL source addr.

__global__ __launch_bounds__(512, 4) void gemm1_k(const float* __restrict__ x,
                                                  const unsigned short* __restrict__ w1t,
                                                  unsigned short* __restrict__ h1) {
    __shared__ __align__(16) float          Asf[2][128 * 32];  // 32 KB
    __shared__ __align__(16) unsigned short Bs[2][256 * 32];   // 32 KB

    const int t = threadIdx.x;
    const int wv = t >> 6, lane = t & 63;
    const int lg = lane >> 4, lr = lane & 15;
    const int wm = wv >> 2, wn = wv & 3;

    const int arow0 = t >> 3;
    const int achk = (t & 7) ^ (arow0 & 7);
    size_t g0 = (size_t)blockIdx.x * 128 + arow0;
    size_t g1 = g0 + 64;
    if (g0 > N_NODES - 1) g0 = N_NODES - 1;
    if (g1 > N_NODES - 1) g1 = N_NODES - 1;
    const float* asrc0 = x + g0 * F_IN + achk * 4;
    const float* asrc1 = x + g1 * F_IN + achk * 4;
    const unsigned short* bsrc0 = w1t + (size_t)(t >> 2) * F_IN + (t & 3) * 8;
    const unsigned short* bsrc1 = bsrc0 + 128 * F_IN;

#define STAGE(bf, ks)                                                         \
    do { const int _o = (ks) * 32;                                            \
        GLOAD16(asrc0 + _o, &Asf[bf][t * 4]);                                 \
        GLOAD16(asrc1 + _o, &Asf[bf][t * 4 + 2048]);                          \
        GLOAD16(bsrc0 + _o, &Bs[bf][t * 8]);                                  \
        GLOAD16(bsrc1 + _o, &Bs[bf][(t + 512) * 8]);                          \
    } while (0)

    f32x4 acc[4][4] = {};

    STAGE(0, 0);                       // 4 outstanding

    for (int ks = 0; ks < 16; ++ks) {
        const int bf = ks & 1;
        if (ks < 15) {
            STAGE(bf ^ 1, ks + 1);     // <=8 outstanding
            asm volatile("s_waitcnt vmcnt(4)" ::: "memory");  // buf-ks landed
        } else {
            asm volatile("s_waitcnt vmcnt(0)" ::: "memory");  // last: full drain
        }
        __builtin_amdgcn_sched_barrier(0);
        __builtin_amdgcn_s_barrier();  // bar1: buf-ks visible to all waves

        short8 afr[4], bfr[4];
#pragma unroll
        for (int mi = 0; mi < 4; ++mi) {
            const int r = wm * 64 + mi * 16 + lr;
            const int s = r & 7;
            const float* base = &Asf[bf][r * 32];
            f32x4 lo = *(const f32x4*)(base + (((lg * 2) ^ s) * 4));
            f32x4 hi = *(const f32x4*)(base + (((lg * 2 + 1) ^ s) * 4));
            short8 a;
            a[0] = (short)hx(lo[0]); a[1] = (short)hx(lo[1]);
            a[2] = (short)hx(lo[2]); a[3] = (short)hx(lo[3]);
            a[4] = (short)hx(hi[0]); a[5] = (short)hx(hi[1]);
            a[6] = (short)hx(hi[2]); a[7] = (short)hx(hi[3]);
            afr[mi] = a;
        }
#pragma unroll
        for (int ni = 0; ni < 4; ++ni)
            bfr[ni] = *(const short8*)&Bs[bf][(wn * 64 + ni * 16 + lr) * 32 + lg * 8];
#pragma unroll
        for (int mi = 0; mi < 4; ++mi)
#pragma unroll
            for (int ni = 0; ni < 4; ++ni)
                acc[mi][ni] = __builtin_amdgcn_mfma_f32_16x16x32_bf16(
                    afr[mi], bfr[ni], acc[mi][ni], 0, 0, 0);

        asm volatile("s_waitcnt lgkmcnt(0)" ::: "memory");  // LDS reads done
        __builtin_amdgcn_sched_barrier(0);
        __builtin_amdgcn_s_barrier();  // bar2: safe to overwrite next buffer
    }
#undef STAGE

    // C layout: col=lane&15, row=(lane>>4)*4+reg; h1 padded -> no guards
    const size_t rbase = (size_t)blockIdx.x * 128 + wm * 64 + lg * 4;
#pragma unroll
    for (int mi = 0; mi < 4; ++mi)
#pragma unroll
        for (int ni = 0; ni < 4; ++ni)
#pragma unroll
            for (int j = 0; j < 4; ++j)
                h1[(rbase + mi * 16 + j) * H_DIM + wn * 64 + ni * 16 + lr] =
                    f2bf(acc[mi][ni][j]);
}

// ---------- Aggregation layer 1: h1a = bf16(relu(Anorm@h1+b1)) -------------
// 1 wave per dst node; half-wave (32 lanes x us8 = full 512B row) per edge;
// halves process even/odd edges (4-deep ILP), combined by shfl_xor(32).

__global__ __launch_bounds__(256) void agg1_k(const unsigned short* __restrict__ h1,
                                              const int* __restrict__ rowoff,
                                              const int* __restrict__ bsum,
                                              const int2* __restrict__ colnorm,
                                              const float* __restrict__ dinv,
                                              const float* __restrict__ b1,
                                              unsigned short* __restrict__ h1a,
                                              int E) {
    int wv = threadIdx.x >> 6, lane = threadIdx.x & 63;
    int node = blockIdx.x * 4 + wv;
    if (node >= N_NODES) return;
    int half = lane >> 5;
    int fl = (lane & 31) * 8;
    int beg = row_beg(rowoff, bsum, node);
    int end = row_end(rowoff, bsum, node, E);
    float a[8] = {0.f, 0.f, 0.f, 0.f, 0.f, 0.f, 0.f, 0.f};
    const unsigned short* base = h1 + fl;

    int e = beg + half;
    while (e + 6 < end) {
        int2 c[4];
        us8 v[4];
#pragma unroll
        for (int q = 0; q < 4; ++q) c[q] = colnorm[e + q * 2];
#pragma unroll
        for (int q = 0; q < 4; ++q)
            v[q] = *(const us8*)(base + (long long)c[q].x * H_DIM);
#pragma unroll
        for (int q = 0; q < 4; ++q) {
            float n = __int_as_float(c[q].y);
#pragma unroll
            for (int j = 0; j < 8; ++j) a[j] += n * bf2f(v[q][j]);
        }
        e += 8;
    }
    while (e < end) {
        int2 c0 = colnorm[e];
        us8 v0 = *(const us8*)(base + (long long)c0.x * H_DIM);
        float n0 = __int_as_float(c0.y);
#pragma unroll
        for (int j = 0; j < 8; ++j) a[j] += n0 * bf2f(v0[j]);
        e += 2;
    }
#pragma unroll
    for (int j = 0; j < 8; ++j)
        a[j] += __shfl_xor(a[j], 32);

    if (half == 0) {
        float dn = dinv[node];
        float sn = dn * dn;
        us8 vs = *(const us8*)(base + (long long)node * H_DIM);
        float4 b0 = *(const float4*)(b1 + fl);
        float4 b4 = *(const float4*)(b1 + fl + 4);
        float bb[8] = {b0.x, b0.y, b0.z, b0.w, b4.x, b4.y, b4.z, b4.w};
        us8 o;
#pragma unroll
        for (int j = 0; j < 8; ++j) {
            float r = fmaxf(a[j] + sn * bf2f(vs[j]) + bb[j], 0.f);
            o[j] = f2bf(r);
        }
        *(us8*)(h1a + (long long)node * H_DIM + fl) = o;
    }
}

// ---------- GEMM2: h2[50000x16] = h1a @ W2 (MFMA straight from global) ----

__global__ __launch_bounds__(256) void gemm2_k(const unsigned short* __restrict__ h1a,
                                               const unsigned short* __restrict__ w2t,
                                               float* __restrict__ h2) {
    int t = threadIdx.x;
    int wv = t >> 6, lane = t & 63, lg = lane >> 4, lr = lane & 15;
    int rbase = blockIdx.x * 64 + wv * 16;
    int rr = rbase + lr;
    int rc = rr < N_NODES ? rr : N_NODES - 1;
    f32x4 acc = {0.f, 0.f, 0.f, 0.f};
#pragma unroll
    for (int ks = 0; ks < 8; ++ks) {
        short8 a = *(const short8*)(h1a + (long long)rc * H_DIM + ks * 32 + lg * 8);
        short8 b = *(const short8*)(w2t + lr * H_DIM + ks * 32 + lg * 8);
        acc = __builtin_amdgcn_mfma_f32_16x16x32_bf16(a, b, acc, 0, 0, 0);
    }
#pragma unroll
    for (int j = 0; j < 4; ++j) {
        int row = rbase + lg * 4 + j;
        if (row < N_NODES) h2[(long long)row * C_DIM + lr] = acc[j];
    }
}

// ---------- Aggregation layer 2: out = A_norm @ h2 + b2 (fp32) ----------

__global__ __launch_bounds__(256) void agg2_k(const float* __restrict__ h2,
                                              const int* __restrict__ rowoff,
                                              const int* __restrict__ bsum,
                                              const int2* __restrict__ colnorm,
                                              const float* __restrict__ dinv,
                                              const float* __restrict__ b2,
                                              float* __restrict__ out, int E) {
    int g = threadIdx.x >> 4, c = threadIdx.x & 15;
    int node = blockIdx.x * 16 + g;
    if (node >= N_NODES) return;
    int beg = row_beg(rowoff, bsum, node);
    int end = row_end(rowoff, bsum, node, E);
    float acc = 0.f;
    int e = beg;
    for (; e + 3 < end; e += 4) {
        int2 cn0 = colnorm[e];
        int2 cn1 = colnorm[e + 1];
        int2 cn2 = colnorm[e + 2];
        int2 cn3 = colnorm[e + 3];
        float v0 = h2[(long long)cn0.x * C_DIM + c];
        float v1 = h2[(long long)cn1.x * C_DIM + c];
        float v2 = h2[(long long)cn2.x * C_DIM + c];
        float v3 = h2[(long long)cn3.x * C_DIM + c];
        acc += __int_as_float(cn0.y) * v0 + __int_as_float(cn1.y) * v1
             + __int_as_float(cn2.y) * v2 + __int_as_float(cn3.y) * v3;
    }
    for (; e < end; ++e) {
        int2 cn = colnorm[e];
        acc += __int_as_float(cn.y) * h2[(long long)cn.x * C_DIM + c];
    }
    float dn = dinv[node];
    acc += dn * dn * h2[(long long)node * C_DIM + c];
    out[(long long)node * C_DIM + c] = acc + b2[c];
}

// ---------- launch ----------

extern "C" void kernel_launch(void* const* d_in, const int* in_sizes, int n_in,
                              void* d_out, int out_size, void* d_ws, size_t ws_size,
                              hipStream_t stream) {
    const float* x  = (const float*)d_in[0];
    const void*  ei = d_in[1];
    const float* W1 = (const float*)d_in[2];
    const float* b1 = (const float*)d_in[3];
    const float* W2 = (const float*)d_in[4];
    const float* b2 = (const float*)d_in[5];
    float* out = (float*)d_out;
    long long E = (long long)in_sizes[1] / 2;

    char* w = (char*)d_ws;
    auto alloc = [&](size_t bytes) -> char* {
        char* p = w;
        w += (bytes + 255) & ~(size_t)255;
        return p;
    };
    int*   flag    = (int*)   alloc(4);
    int*   cnt     = (int*)   alloc((size_t)N_NODES * 4);
    int*   cur     = (int*)   alloc((size_t)N_NODES * 4);
    float* dinv    = (float*) alloc((size_t)N_NODES * 4);
    int*   rowoff  = (int*)   alloc((size_t)N_NODES * 4);
    int*   bsum    = (int*)   alloc(512 * 4);
    int2*  colnorm = (int2*)  alloc((size_t)E * 8);
    unsigned short* w1t = (unsigned short*)alloc((size_t)H_DIM * F_IN * 2);
    unsigned short* w2t = (unsigned short*)alloc((size_t)C_DIM * H_DIM * 2);
    unsigned short* h1  = (unsigned short*)alloc((size_t)N_PAD * H_DIM * 2);   // 25.6 MB
    unsigned short* h1a = (unsigned short*)alloc((size_t)N_NODES * H_DIM * 2); // 25.6 MB
    float* h2 = (float*)alloc((size_t)N_NODES * C_DIM * 4);

    prep_k<<<(F_IN * H_DIM + 255) / 256, 256, 0, stream>>>(ei, flag, W1, w1t, W2, w2t,
                                                           cnt, cur);

    int egrid = (int)((E + 255) / 256);
    hist_k<<<egrid, 256, 0, stream>>>(ei, flag, cnt, E);
    int sgrid = (N_NODES + 511) / 512;   // 98 (<=128 for scan2)
    scan1_k<<<sgrid, 512, 0, stream>>>(cnt, rowoff, bsum, dinv, N_NODES);
    scan2_k<<<1, 128, 0, stream>>>(bsum, sgrid);
    scatter_k<<<egrid, 256, 0, stream>>>(ei, flag, dinv, rowoff, bsum, cur, E, colnorm);

    gemm1_k<<<N_PAD / 128, 512, 0, stream>>>(x, w1t, h1);
    agg1_k<<<(N_NODES + 3) / 4, 256, 0, stream>>>(h1, rowoff, bsum, colnorm, dinv,
                                                  b1, h1a, (int)E);
    gemm2_k<<<(N_NODES + 63) / 64, 256, 0, stream>>>(h1a, w2t, h2);
    agg2_k<<<(N_NODES + 15) / 16, 256, 0, stream>>>(h2, rowoff, bsum, colnorm, dinv,
                                                    b2, out, (int)E);
}